// Round 3
// baseline (175.321 us; speedup 1.0000x reference)
//
#include <hip/hip_runtime.h>
#include <cstddef>

typedef _Float16 f16;
typedef __attribute__((ext_vector_type(8))) _Float16 f16x8;
typedef __attribute__((ext_vector_type(4))) float f32x4;

namespace {
constexpr int kB = 16;
constexpr int kN = 2048;
constexpr int kD = 256;   // D_IN
constexpr int kC = 32;
constexpr int kH = 64;
constexpr int kHeads = 4;
constexpr int kKD = 64;
constexpr int kChunks = 32;                  // n-chunks per b
constexpr int kRows = kN / kChunks;          // 64 rows per chunk
constexpr int kXJ = 64;                      // xpart sub-chunks (fallback path)

// workspace offsets (floats)
constexpr size_t OFF_XPART = 0;                       // fused: [B,32,D]; fallback: [B,64,D]
constexpr size_t OFF_V     = OFF_XPART + 262144;      // [B,C,H]
constexpr size_t OFF_WV    = OFF_V + 32768;           // [B,C,D] fp32
constexpr size_t OFF_BV    = OFF_WV + 131072;         // [B,C]
constexpr size_t OFF_Y     = OFF_BV + 512;            // [B,C,D] (fallback atomic)
constexpr size_t OFF_CS    = OFF_Y + 131072;          // [B,C]
constexpr size_t OFF_BAR   = OFF_CS + 512;            // barrier counters (16 × 16 ints)
constexpr size_t OFF_CTX   = OFF_BAR + 393216;        // [B,C,HEADS,KD]
constexpr size_t OFF_XF16  = OFF_CTX + 524288;        // [B,N,D] f16 (fallback only)
constexpr size_t OFF_WVH   = OFF_XF16 + 4194304;      // [B,C,D] f16
constexpr size_t OFF_CSP   = OFF_WVH + 65536;         // [B,chunks,C]
constexpr size_t OFF_YP    = OFF_CSP + 16384;         // [B,chunks,C,D] f16
constexpr size_t WS_NEED_PARTIAL = (OFF_YP + 4194304) * sizeof(float);

struct SMemR {                       // routing phases (A-F)
  f16 xsT[kD][kRows + 8];            // [256][72] transposed x (persistent A->E)
  float aL[kRows][kC + 4];           // [64][36] logits
  f16 pT[kC][kRows + 8];             // [32][72] P^T
  float csL[8][kC];
  float yL[kD];
  float sL[4][kH];
  float vL[kH];
  float csLs;
};
struct SMemA {                       // attention phase
  float rL[kC * kH];
  float qL[kC][kKD];
  float kL[kC][kKD + 1];
  float vL[kC][kKD];
  float sc[kC][kC + 1];
};
struct SMemF {                       // final phase
  float cL[kHeads * kKD];
  float sL[4][kH];
};
union SMemU { SMemR r; SMemA a; SMemF f; };
}  // namespace

// ---- per-b barrier: 32 blocks of batch b rendezvous. Monotonic epoch counter,
// agent-scope release/acquire (leader pattern: syncthreads drains each wave's
// vmcnt first; leader's release writes back L2, acquire invalidates L1/L2).
// Bounded spin: on pathological non-residency we break (numeric fail, no hang).
__device__ __forceinline__ void bbar(int* __restrict__ bar, int b, int target) {
  __syncthreads();
  if (threadIdx.x == 0) {
    __hip_atomic_fetch_add(&bar[b * 16], 1, __ATOMIC_RELEASE,
                           __HIP_MEMORY_SCOPE_AGENT);
    int guard = 0;
    while (__hip_atomic_load(&bar[b * 16], __ATOMIC_ACQUIRE,
                             __HIP_MEMORY_SCOPE_AGENT) < target) {
      __builtin_amdgcn_s_sleep(1);
      if (++guard > (1 << 22)) break;
    }
  }
  __syncthreads();
}

// squash tail shared by sv phases. Requires sm.yL/csLs valid + __syncthreads done.
template <int CW, int ACC, int WRV>
__device__ __forceinline__ void sv_tail(const float* __restrict__ W,
                                        const float* __restrict__ b_caps,
                                        SMemR& r, float* __restrict__ v,
                                        float* __restrict__ Wv, f16* __restrict__ wvh,
                                        float* __restrict__ bv, int b, int c, int t) {
  const int w = t >> 6, h = t & 63;
  const float* Wc = W + (size_t)c * kD * kH;
  {
    float acc = 0.f;
#pragma unroll 8
    for (int d = w * 64; d < (w + 1) * 64; ++d)
      acc = fmaf(r.yL[d], Wc[(size_t)d * kH + h], acc);
    r.sL[w][h] = acc;
  }
  __syncthreads();
  if (t < 64) {
    const float bch = b_caps[c * kH + h];
    float s = r.sL[0][h] + r.sL[1][h] + r.sL[2][h] + r.sL[3][h] + r.csLs * bch;
    float s2 = s * s;
#pragma unroll
    for (int off = 32; off; off >>= 1) s2 += __shfl_xor(s2, off, 64);
    const float scale = s2 / (1.f + s2) * rsqrtf(s2 + 1e-7f);
    const float vh = scale * s;
    if (WRV) v[((size_t)b * kC + c) * kH + h] = vh;
    r.vL[h] = vh;
    if (CW) {
      float bvp = bch * vh;
#pragma unroll
      for (int off = 32; off; off >>= 1) bvp += __shfl_xor(bvp, off, 64);
      if (h == 0) bv[b * kC + c] = ACC ? (bv[b * kC + c] + bvp) : bvp;
    }
  }
  __syncthreads();
  if (CW) {
    float acc = 0.f;
    const float* Wrow = Wc + (size_t)t * kH;
#pragma unroll 8
    for (int hh = 0; hh < kH; ++hh) acc = fmaf(Wrow[hh], r.vL[hh], acc);
    const size_t idx = ((size_t)b * kC + c) * kD + t;
    const float nv = ACC ? (Wv[idx] + acc) : acc;
    Wv[idx] = nv;
    wvh[idx] = (f16)nv;
  }
}

// one routing iteration: GEMM1(af regs, wvh) -> softmax -> GEMM2(pT, xsT) -> partials
__device__ __forceinline__ void route_phase(SMemR& r, const f16x8* __restrict__ af,
                                            const f16* __restrict__ wvh,
                                            const float* __restrict__ bv,
                                            f16* __restrict__ yp, float* __restrict__ csp,
                                            int b, int chunk, int t) {
  const int lane = t & 63, w = t >> 6;
  const int l15 = lane & 15, q = lane >> 4;
  const float bvc = bv[b * kC + (t & 31)];

  f32x4 acc0 = {0.f, 0.f, 0.f, 0.f}, acc1 = {0.f, 0.f, 0.f, 0.f};
  {
    const f16x8* B0 = reinterpret_cast<const f16x8*>(
        wvh + ((size_t)(b * kC + l15)) * kD + q * 8);
    const f16x8* B1 = reinterpret_cast<const f16x8*>(
        wvh + ((size_t)(b * kC + 16 + l15)) * kD + q * 8);
#pragma unroll
    for (int ks = 0; ks < 8; ++ks) {
      acc0 = __builtin_amdgcn_mfma_f32_16x16x32_f16(af[ks], B0[ks * 4], acc0, 0, 0, 0);
      acc1 = __builtin_amdgcn_mfma_f32_16x16x32_f16(af[ks], B1[ks * 4], acc1, 0, 0, 0);
    }
  }
#pragma unroll
  for (int rr = 0; rr < 4; ++rr) {
    r.aL[w * 16 + q * 4 + rr][l15] = acc0[rr];
    r.aL[w * 16 + q * 4 + rr][16 + l15] = acc1[rr];
  }
  __syncthreads();  // aL visible

  const int c = t & 31, sg = t >> 5;
  float csreg = 0.f;
#pragma unroll
  for (int k = 0; k < 8; ++k) {
    const int rr = sg * 8 + k;
    float L = bvc + r.aL[rr][c];
    float m = L;
#pragma unroll
    for (int off = 16; off; off >>= 1) m = fmaxf(m, __shfl_xor(m, off, 64));
    const float e = __expf(L - m);
    float ssum = e;
#pragma unroll
    for (int off = 16; off; off >>= 1) ssum += __shfl_xor(ssum, off, 64);
    const float p = e / ssum;
    r.pT[c][rr] = (f16)p;
    csreg += p;
  }
  r.csL[sg][c] = csreg;
  __syncthreads();  // pT visible

  const int mt2 = w & 1;
  const int ntb = (w >> 1) * 8;
  const f16x8 a0 = *reinterpret_cast<const f16x8*>(&r.pT[mt2 * 16 + l15][q * 8]);
  const f16x8 a1 = *reinterpret_cast<const f16x8*>(&r.pT[mt2 * 16 + l15][32 + q * 8]);
  const int cap = mt2 * 16 + q * 4;
#pragma unroll
  for (int i = 0; i < 8; ++i) {
    const int d0 = (ntb + i) * 16;
    const f16x8 b0 = *reinterpret_cast<const f16x8*>(&r.xsT[d0 + l15][q * 8]);
    const f16x8 b1 = *reinterpret_cast<const f16x8*>(&r.xsT[d0 + l15][32 + q * 8]);
    f32x4 o = {0.f, 0.f, 0.f, 0.f};
    o = __builtin_amdgcn_mfma_f32_16x16x32_f16(a0, b0, o, 0, 0, 0);
    o = __builtin_amdgcn_mfma_f32_16x16x32_f16(a1, b1, o, 0, 0, 0);
    f16* dst = yp + (((size_t)(b * kChunks + chunk)) * kC + cap) * kD + d0 + l15;
#pragma unroll
    for (int rr = 0; rr < 4; ++rr) dst[(size_t)rr * kD] = (f16)o[rr];
  }
  if (t < 32) {
    float s = 0.f;
#pragma unroll
    for (int j = 0; j < 8; ++j) s += r.csL[j][t];
    csp[((size_t)b * kChunks + chunk) * kC + t] = s;
  }
}

__global__ __launch_bounds__(256, 2) void k_all(
    const float* __restrict__ x, const float* __restrict__ W,
    const float* __restrict__ b_caps, const float* __restrict__ gamma,
    const float* __restrict__ Wq, const float* __restrict__ bq,
    const float* __restrict__ Wk, const float* __restrict__ bk,
    const float* __restrict__ Wvp, const float* __restrict__ bvp,
    const float* __restrict__ Wo, const float* __restrict__ bo,
    const float* __restrict__ ln_g, const float* __restrict__ ln_b,
    float* __restrict__ out, float* __restrict__ ws) {
  float* xpart = ws + OFF_XPART;   // [B,32,D] per-chunk column sums
  float* v     = ws + OFF_V;
  float* Wv    = ws + OFF_WV;
  float* bv    = ws + OFF_BV;
  int*   bar   = (int*)(ws + OFF_BAR);
  float* ctx   = ws + OFF_CTX;
  f16*   wvh   = (f16*)(ws + OFF_WVH);
  float* csp   = ws + OFF_CSP;
  f16*   yp    = (f16*)(ws + OFF_YP);

  const int b = blockIdx.x, chunk = blockIdx.y;
  const int t = threadIdx.x;
  const int lane = t & 63, w = t >> 6;
  const int l15 = lane & 15, q = lane >> 4;
  const int n0 = chunk * kRows;
  const int c = chunk;  // capsule index for sv phases

  __shared__ __align__(16) SMemU sm;

  // ---- Phase A: column partial sums (fp32) + stage x chunk: af regs + xsT LDS
  {
    const float* xc = x + ((size_t)b * kN + n0) * kD + t;
    float s = 0.f;
#pragma unroll 16
    for (int n = 0; n < kRows; ++n) s += xc[(size_t)n * kD];
    xpart[((size_t)b * kChunks + chunk) * kD + t] = s;
  }
  f16x8 af[8];
  {
    const int row = w * 16 + l15;
    const float* xr = x + ((size_t)(b * kN + n0 + row)) * kD + q * 8;
#pragma unroll
    for (int ks = 0; ks < 8; ++ks) {
      const f32x4* p = reinterpret_cast<const f32x4*>(xr + ks * 32);
      const f32x4 lo = p[0], hi = p[1];
      f16x8 a;
      a[0] = (f16)lo[0]; a[1] = (f16)lo[1]; a[2] = (f16)lo[2]; a[3] = (f16)lo[3];
      a[4] = (f16)hi[0]; a[5] = (f16)hi[1]; a[6] = (f16)hi[2]; a[7] = (f16)hi[3];
      af[ks] = a;
      const int dbase = ks * 32 + q * 8;
#pragma unroll
      for (int i = 0; i < 8; ++i) {
        const int ii = (i + 2 * q) & 7;  // rotate: distinct banks across q-groups
        sm.r.xsT[dbase + ii][row] = a[ii];
      }
    }
  }
  bbar(bar, b, 32 * 1);

  // ---- Phase B: sv mode0 (y = colsum/C), compute v, Wv, wvh, bv
  {
    float s = 0.f;
#pragma unroll 8
    for (int ch = 0; ch < kChunks; ++ch)
      s += xpart[((size_t)b * kChunks + ch) * kD + t];
    sm.r.yL[t] = s * (1.f / (float)kC);
    if (t == 0) sm.r.csLs = (float)kN / (float)kC;
  }
  __syncthreads();
  sv_tail<1, 0, 0>(W, b_caps, sm.r, v, Wv, wvh, bv, b, c, t);
  bbar(bar, b, 32 * 2);

  // ---- Phase C: routing iteration 1
  route_phase(sm.r, af, wvh, bv, yp, csp, b, chunk, t);
  bbar(bar, b, 32 * 3);

  // ---- Phase D: sv from partials, accumulate Wv/bv
  {
    float s = 0.f;
#pragma unroll 8
    for (int ch = 0; ch < kChunks; ++ch)
      s += (float)yp[(((size_t)b * kChunks + ch) * kC + c) * kD + t];
    sm.r.yL[t] = s;
    if (t < 32) {
      float cs_ = csp[((size_t)b * kChunks + t) * kC + c];
#pragma unroll
      for (int off = 16; off; off >>= 1) cs_ += __shfl_xor(cs_, off, 64);
      if (t == 0) sm.r.csLs = cs_;
    }
  }
  __syncthreads();
  sv_tail<1, 1, 0>(W, b_caps, sm.r, v, Wv, wvh, bv, b, c, t);
  bbar(bar, b, 32 * 4);

  // ---- Phase E: routing iteration 2
  route_phase(sm.r, af, wvh, bv, yp, csp, b, chunk, t);
  bbar(bar, b, 32 * 5);

  // ---- Phase F: final sv -> v (routed) to global
  {
    float s = 0.f;
#pragma unroll 8
    for (int ch = 0; ch < kChunks; ++ch)
      s += (float)yp[(((size_t)b * kChunks + ch) * kC + c) * kD + t];
    sm.r.yL[t] = s;
    if (t < 32) {
      float cs_ = csp[((size_t)b * kChunks + t) * kC + c];
#pragma unroll
      for (int off = 16; off; off >>= 1) cs_ += __shfl_xor(cs_, off, 64);
      if (t == 0) sm.r.csLs = cs_;
    }
  }
  __syncthreads();
  sv_tail<0, 0, 1>(W, b_caps, sm.r, v, Wv, wvh, bv, b, c, t);
  bbar(bar, b, 32 * 6);

  // ---- Phase G: attention (blocks with chunk < kHeads participate; head = chunk)
  if (chunk < kHeads) {
    const int head = chunk;
    const int kk = t & 63;
#pragma unroll
    for (int i = 0; i < 8; ++i)
      sm.a.rL[t + 256 * i] = v[(size_t)b * kC * kH + t + 256 * i];
    __syncthreads();
    float aq[8], ak[8], av[8];
    const float bbq = bq[head * kKD + kk];
    const float bbk = bk[head * kKD + kk];
    const float bbv = bvp[head * kKD + kk];
#pragma unroll
    for (int i = 0; i < 8; ++i) { aq[i] = bbq; ak[i] = bbk; av[i] = bbv; }
#pragma unroll 4
    for (int hh = 0; hh < kH; ++hh) {
      const size_t widx = ((size_t)hh * kHeads + head) * kKD + kk;
      const float wq = Wq[widx];
      const float wk2 = Wk[widx];
      const float wv2 = Wvp[widx];
#pragma unroll
      for (int i = 0; i < 8; ++i) {
        const float rv = sm.a.rL[(w + 4 * i) * kH + hh];
        aq[i] = fmaf(rv, wq, aq[i]);
        ak[i] = fmaf(rv, wk2, ak[i]);
        av[i] = fmaf(rv, wv2, av[i]);
      }
    }
#pragma unroll
    for (int i = 0; i < 8; ++i) {
      const int cc = w + 4 * i;
      sm.a.qL[cc][kk] = aq[i];
      sm.a.kL[cc][kk] = ak[i];
      sm.a.vL[cc][kk] = av[i];
    }
    __syncthreads();
#pragma unroll
    for (int i = 0; i < 4; ++i) {
      const int e = t + 256 * i, qc = e >> 5, kc2 = e & 31;
      float s = 0.f;
#pragma unroll 8
      for (int d = 0; d < kKD; ++d) s = fmaf(sm.a.qL[qc][d], sm.a.kL[kc2][d], s);
      sm.a.sc[qc][kc2] = s * 0.125f;
    }
    __syncthreads();
    if (t < kC) {
      float m = -1e30f;
#pragma unroll
      for (int kc2 = 0; kc2 < kC; ++kc2) m = fmaxf(m, sm.a.sc[t][kc2]);
      float ssum = 0.f;
#pragma unroll
      for (int kc2 = 0; kc2 < kC; ++kc2) {
        const float e2 = __expf(sm.a.sc[t][kc2] - m);
        sm.a.sc[t][kc2] = e2;
        ssum += e2;
      }
      const float inv = 1.f / ssum;
#pragma unroll
      for (int kc2 = 0; kc2 < kC; ++kc2) sm.a.sc[t][kc2] *= inv;
    }
    __syncthreads();
#pragma unroll
    for (int i = 0; i < 8; ++i) {
      const int e = t + 256 * i, qc = e >> 6, d = e & 63;
      float s = 0.f;
#pragma unroll 8
      for (int kc2 = 0; kc2 < kC; ++kc2) s = fmaf(sm.a.sc[qc][kc2], sm.a.vL[kc2][d], s);
      ctx[(((size_t)b * kC + qc) * kHeads + head) * kKD + d] = s;
    }
  }
  bbar(bar, b, 32 * 7);

  // ---- Phase H: out-proj + residual + LN + squash*gamma (block = (b, c))
  {
    const int bc = b * kC + chunk;
    const int h = t & 63;
    sm.f.cL[t] = ctx[(size_t)bc * (kHeads * kKD) + t];
    __syncthreads();
    float acc = 0.f;
#pragma unroll 8
    for (int nd = w * 64; nd < (w + 1) * 64; ++nd)
      acc = fmaf(sm.f.cL[nd], Wo[(size_t)nd * kH + h], acc);
    sm.f.sL[w][h] = acc;
    __syncthreads();
    if (t < 64) {
      const float yv = sm.f.sL[0][h] + sm.f.sL[1][h] + sm.f.sL[2][h] + sm.f.sL[3][h] +
                       bo[h] + v[(size_t)bc * kH + h];
      float mu = yv;
#pragma unroll
      for (int off = 32; off; off >>= 1) mu += __shfl_xor(mu, off, 64);
      mu *= (1.f / (float)kH);
      const float dv = yv - mu;
      float var = dv * dv;
#pragma unroll
      for (int off = 32; off; off >>= 1) var += __shfl_xor(var, off, 64);
      var *= (1.f / (float)kH);
      const float nrm = dv * rsqrtf(var + 1e-3f) * ln_g[h] + ln_b[h];
      float s2 = nrm * nrm;
#pragma unroll
      for (int off = 32; off; off >>= 1) s2 += __shfl_xor(s2, off, 64);
      const float scale = s2 / (1.f + s2) * rsqrtf(s2 + 1e-7f);
      out[(size_t)bc * kH + h] = scale * nrm * gamma[0];
    }
  }
}

// ======================= fallback multi-kernel path (round-1, verified) =======================

__global__ __launch_bounds__(256) void k_xpart(const float* __restrict__ x,
                                               float* __restrict__ xpart,
                                               f16* __restrict__ xh) {
  const int b = blockIdx.x, j = blockIdx.y, d = threadIdx.x;
  const size_t base = ((size_t)b * kN + (size_t)j * 32) * kD + d;
  const float* xp = x + base;
  f16* xo = xh + base;
  float s = 0.f;
#pragma unroll
  for (int n = 0; n < 32; ++n) {
    const float v = xp[(size_t)n * kD];
    s += v;
    xo[(size_t)n * kD] = (f16)v;
  }
  xpart[((size_t)b * kXJ + j) * kD + d] = s;
}

__global__ __launch_bounds__(256) void k_sv(
    const float* __restrict__ W, const float* __restrict__ b_caps,
    const float* __restrict__ xpart, const float* __restrict__ y,
    const float* __restrict__ csum, const f16* __restrict__ ypart,
    const float* __restrict__ cspart, float* __restrict__ v,
    float* __restrict__ Wv, f16* __restrict__ Wvh, float* __restrict__ bv,
    const int mode, const int computeWv, const int accWv, const int npart) {
  const int bc = blockIdx.x, b = bc >> 5, c = bc & 31;
  const int t = threadIdx.x;
  const int w = t >> 6, h = t & 63;
  __shared__ float yL[kD];
  __shared__ float sL[4][kH];
  __shared__ float vL[kH];
  __shared__ float csLs;

  if (mode == 0) {
    float s = 0.f;
#pragma unroll 8
    for (int j = 0; j < kXJ; ++j) s += xpart[((size_t)b * kXJ + j) * kD + t];
    yL[t] = s * (1.f / (float)kC);
    if (t == 0) csLs = (float)kN / (float)kC;
  } else if (npart > 0) {
    float s = 0.f;
#pragma unroll 8
    for (int ch = 0; ch < kChunks; ++ch)
      s += (float)ypart[(((size_t)b * kChunks + ch) * kC + c) * kD + t];
    yL[t] = s;
    if (t < 32) {
      float cs_ = cspart[((size_t)b * kChunks + t) * kC + c];
#pragma unroll
      for (int off = 16; off; off >>= 1) cs_ += __shfl_xor(cs_, off, 64);
      if (t == 0) csLs = cs_;
    }
  } else {
    yL[t] = y[(size_t)bc * kD + t];
    if (t == 0) csLs = csum[bc];
  }
  __syncthreads();

  const float* Wc = W + (size_t)c * kD * kH;
  {
    float acc = 0.f;
#pragma unroll 8
    for (int d = w * 64; d < (w + 1) * 64; ++d)
      acc = fmaf(yL[d], Wc[(size_t)d * kH + h], acc);
    sL[w][h] = acc;
  }
  __syncthreads();

  if (t < 64) {
    const float bch = b_caps[c * kH + h];
    float s = sL[0][h] + sL[1][h] + sL[2][h] + sL[3][h] + csLs * bch;
    float s2 = s * s;
#pragma unroll
    for (int off = 32; off; off >>= 1) s2 += __shfl_xor(s2, off, 64);
    const float scale = s2 / (1.f + s2) * rsqrtf(s2 + 1e-7f);
    const float vh = scale * s;
    v[(size_t)bc * kH + h] = vh;
    vL[h] = vh;
    if (computeWv) {
      float bvp = bch * vh;
#pragma unroll
      for (int off = 32; off; off >>= 1) bvp += __shfl_xor(bvp, off, 64);
      if (h == 0) bv[bc] = accWv ? (bv[bc] + bvp) : bvp;
    }
  }
  __syncthreads();
  if (computeWv) {
    float acc = 0.f;
    const float* Wrow = Wc + (size_t)t * kH;
#pragma unroll 8
    for (int hh = 0; hh < kH; ++hh) acc = fmaf(Wrow[hh], vL[hh], acc);
    const size_t idx = (size_t)bc * kD + t;
    const float nv = accWv ? (Wv[idx] + acc) : acc;
    Wv[idx] = nv;
    Wvh[idx] = (f16)nv;
  }
}

__global__ __launch_bounds__(256) void k_route(
    const f16* __restrict__ xh, const f16* __restrict__ Wvh,
    const float* __restrict__ bv, float* __restrict__ y,
    float* __restrict__ csum, f16* __restrict__ ypart,
    float* __restrict__ cspart, const int usePart) {
  const int b = blockIdx.x, chunk = blockIdx.y;
  const int t = threadIdx.x;
  const int lane = t & 63, w = t >> 6;
  const int l15 = lane & 15, q = lane >> 4;

  __shared__ __align__(16) f16 xsT[kD][kRows + 8];
  __shared__ float aL[kRows][kC + 4];
  __shared__ __align__(16) f16 pT[kC][kRows + 8];
  __shared__ float csL[8][kC];

  const int n0 = chunk * kRows;
  const float bvc = bv[b * kC + (t & 31)];

  f32x4 acc0 = {0.f, 0.f, 0.f, 0.f}, acc1 = {0.f, 0.f, 0.f, 0.f};
  {
    const int row = w * 16 + l15;
    const f16x8* Ar = reinterpret_cast<const f16x8*>(
        xh + ((size_t)(b * kN + n0 + row)) * kD + q * 8);
    const f16x8* B0 = reinterpret_cast<const f16x8*>(
        Wvh + ((size_t)(b * kC + l15)) * kD + q * 8);
    const f16x8* B1 = reinterpret_cast<const f16x8*>(
        Wvh + ((size_t)(b * kC + 16 + l15)) * kD + q * 8);
#pragma unroll
    for (int ks = 0; ks < 8; ++ks) {
      f16x8 af = Ar[ks * 4];
      acc0 = __builtin_amdgcn_mfma_f32_16x16x32_f16(af, B0[ks * 4], acc0, 0, 0, 0);
      acc1 = __builtin_amdgcn_mfma_f32_16x16x32_f16(af, B1[ks * 4], acc1, 0, 0, 0);
      const int dbase = ks * 32 + q * 8;
#pragma unroll
      for (int i = 0; i < 8; ++i) {
        const int ii = (i + 2 * q) & 7;
        xsT[dbase + ii][row] = af[ii];
      }
    }
  }
#pragma unroll
  for (int r = 0; r < 4; ++r) {
    aL[w * 16 + q * 4 + r][l15] = acc0[r];
    aL[w * 16 + q * 4 + r][16 + l15] = acc1[r];
  }
  __syncthreads();

  const int c = t & 31, sg = t >> 5;
  float csreg = 0.f;
#pragma unroll
  for (int k = 0; k < 8; ++k) {
    const int r = sg * 8 + k;
    float L = bvc + aL[r][c];
    float m = L;
#pragma unroll
    for (int off = 16; off; off >>= 1) m = fmaxf(m, __shfl_xor(m, off, 64));
    const float e = __expf(L - m);
    float ssum = e;
#pragma unroll
    for (int off = 16; off; off >>= 1) ssum += __shfl_xor(ssum, off, 64);
    const float p = e / ssum;
    pT[c][r] = (f16)p;
    csreg += p;
  }
  csL[sg][c] = csreg;
  __syncthreads();

  const int mt2 = w & 1;
  const int ntb = (w >> 1) * 8;
  const f16x8 a0 = *reinterpret_cast<const f16x8*>(&pT[mt2 * 16 + l15][q * 8]);
  const f16x8 a1 = *reinterpret_cast<const f16x8*>(&pT[mt2 * 16 + l15][32 + q * 8]);
  const int cap = mt2 * 16 + q * 4;
#pragma unroll
  for (int i = 0; i < 8; ++i) {
    const int d0 = (ntb + i) * 16;
    const f16x8 b0 = *reinterpret_cast<const f16x8*>(&xsT[d0 + l15][q * 8]);
    const f16x8 b1 = *reinterpret_cast<const f16x8*>(&xsT[d0 + l15][32 + q * 8]);
    f32x4 o = {0.f, 0.f, 0.f, 0.f};
    o = __builtin_amdgcn_mfma_f32_16x16x32_f16(a0, b0, o, 0, 0, 0);
    o = __builtin_amdgcn_mfma_f32_16x16x32_f16(a1, b1, o, 0, 0, 0);
    if (usePart) {
      f16* dst = ypart + (((size_t)(b * kChunks + chunk)) * kC + cap) * kD + d0 + l15;
#pragma unroll
      for (int r = 0; r < 4; ++r) dst[(size_t)r * kD] = (f16)o[r];
    } else {
      float* dst = y + ((size_t)(b * kC + cap)) * kD + d0 + l15;
#pragma unroll
      for (int r = 0; r < 4; ++r) atomicAdd(dst + (size_t)r * kD, o[r]);
    }
  }
  if (t < 32) {
    float s = 0.f;
#pragma unroll
    for (int j = 0; j < 8; ++j) s += csL[j][t];
    if (usePart) cspart[((size_t)b * kChunks + chunk) * kC + t] = s;
    else atomicAdd(csum + b * kC + t, s);
  }
}

__global__ __launch_bounds__(256) void k_attn(
    const float* __restrict__ routed,
    const float* __restrict__ Wq, const float* __restrict__ bq,
    const float* __restrict__ Wk, const float* __restrict__ bk,
    const float* __restrict__ Wvp, const float* __restrict__ bvp,
    float* __restrict__ ctx) {
  const int b = blockIdx.x, head = blockIdx.y, t = threadIdx.x;
  const int kk = t & 63, w = t >> 6;
  __shared__ float rL[kC * kH];
  __shared__ float qL[kC][kKD];
  __shared__ float kL[kC][kKD + 1];
  __shared__ float vL[kC][kKD];
  __shared__ float sc[kC][kC + 1];
#pragma unroll
  for (int i = 0; i < 8; ++i) rL[t + 256 * i] = routed[(size_t)b * kC * kH + t + 256 * i];
  __syncthreads();
  float aq[8], ak[8], av[8];
  const float bbq = bq[head * kKD + kk];
  const float bbk = bk[head * kKD + kk];
  const float bbv = bvp[head * kKD + kk];
#pragma unroll
  for (int i = 0; i < 8; ++i) { aq[i] = bbq; ak[i] = bbk; av[i] = bbv; }
#pragma unroll 4
  for (int hh = 0; hh < kH; ++hh) {
    const size_t widx = ((size_t)hh * kHeads + head) * kKD + kk;
    const float wq = Wq[widx];
    const float wk2 = Wk[widx];
    const float wv2 = Wvp[widx];
#pragma unroll
    for (int i = 0; i < 8; ++i) {
      const float r = rL[(w + 4 * i) * kH + hh];
      aq[i] = fmaf(r, wq, aq[i]);
      ak[i] = fmaf(r, wk2, ak[i]);
      av[i] = fmaf(r, wv2, av[i]);
    }
  }
#pragma unroll
  for (int i = 0; i < 8; ++i) {
    const int cc = w + 4 * i;
    qL[cc][kk] = aq[i];
    kL[cc][kk] = ak[i];
    vL[cc][kk] = av[i];
  }
  __syncthreads();
#pragma unroll
  for (int i = 0; i < 4; ++i) {
    const int e = t + 256 * i, qc = e >> 5, kc2 = e & 31;
    float s = 0.f;
#pragma unroll 8
    for (int d = 0; d < kKD; ++d) s = fmaf(qL[qc][d], kL[kc2][d], s);
    sc[qc][kc2] = s * 0.125f;
  }
  __syncthreads();
  if (t < kC) {
    float m = -1e30f;
#pragma unroll
    for (int kc2 = 0; kc2 < kC; ++kc2) m = fmaxf(m, sc[t][kc2]);
    float ssum = 0.f;
#pragma unroll
    for (int kc2 = 0; kc2 < kC; ++kc2) {
      const float e2 = __expf(sc[t][kc2] - m);
      sc[t][kc2] = e2;
      ssum += e2;
    }
    const float inv = 1.f / ssum;
#pragma unroll
    for (int kc2 = 0; kc2 < kC; ++kc2) sc[t][kc2] *= inv;
  }
  __syncthreads();
#pragma unroll
  for (int i = 0; i < 8; ++i) {
    const int e = t + 256 * i, qc = e >> 6, d = e & 63;
    float s = 0.f;
#pragma unroll 8
    for (int kc2 = 0; kc2 < kC; ++kc2) s = fmaf(sc[qc][kc2], vL[kc2][d], s);
    ctx[(((size_t)b * kC + qc) * kHeads + head) * kKD + d] = s;
  }
}

__global__ __launch_bounds__(256) void k_final(
    const float* __restrict__ ctx, const float* __restrict__ Wo,
    const float* __restrict__ bo, const float* __restrict__ routed,
    const float* __restrict__ ln_g, const float* __restrict__ ln_b,
    const float* __restrict__ gamma, float* __restrict__ out) {
  const int bc = blockIdx.x, t = threadIdx.x;
  const int w = t >> 6, h = t & 63;
  __shared__ float cL[kHeads * kKD];
  __shared__ float sL[4][kH];
  cL[t] = ctx[(size_t)bc * (kHeads * kKD) + t];
  __syncthreads();
  float acc = 0.f;
#pragma unroll 8
  for (int nd = w * 64; nd < (w + 1) * 64; ++nd)
    acc = fmaf(cL[nd], Wo[(size_t)nd * kH + h], acc);
  sL[w][h] = acc;
  __syncthreads();
  if (t < 64) {
    const float yv = sL[0][h] + sL[1][h] + sL[2][h] + sL[3][h] + bo[h] +
                     routed[(size_t)bc * kH + h];
    float mu = yv;
#pragma unroll
    for (int off = 32; off; off >>= 1) mu += __shfl_xor(mu, off, 64);
    mu *= (1.f / (float)kH);
    const float dv = yv - mu;
    float var = dv * dv;
#pragma unroll
    for (int off = 32; off; off >>= 1) var += __shfl_xor(var, off, 64);
    var *= (1.f / (float)kH);
    const float nrm = dv * rsqrtf(var + 1e-3f) * ln_g[h] + ln_b[h];
    float s2 = nrm * nrm;
#pragma unroll
    for (int off = 32; off; off >>= 1) s2 += __shfl_xor(s2, off, 64);
    const float scale = s2 / (1.f + s2) * rsqrtf(s2 + 1e-7f);
    out[(size_t)bc * kH + h] = scale * nrm * gamma[0];
  }
}

extern "C" void kernel_launch(void* const* d_in, const int* in_sizes, int n_in,
                              void* d_out, int out_size, void* d_ws, size_t ws_size,
                              hipStream_t stream) {
  (void)in_sizes; (void)n_in; (void)out_size;
  const float* x      = (const float*)d_in[0];
  const float* W      = (const float*)d_in[1];
  const float* b_caps = (const float*)d_in[2];
  const float* gamma  = (const float*)d_in[3];
  const float* Wq     = (const float*)d_in[4];
  const float* bq     = (const float*)d_in[5];
  const float* Wk     = (const float*)d_in[6];
  const float* bk     = (const float*)d_in[7];
  const float* Wv_in  = (const float*)d_in[8];
  const float* bv_in  = (const float*)d_in[9];
  const float* Wo     = (const float*)d_in[10];
  const float* bo     = (const float*)d_in[11];
  const float* ln_g   = (const float*)d_in[12];
  const float* ln_b   = (const float*)d_in[13];
  float* out = (float*)d_out;
  float* ws  = (float*)d_ws;

  // one-time co-residency check for the persistent fused kernel (regular launch)
  static int s_ok = -1;
  if (s_ok < 0) {
    int dev = 0;
    hipGetDevice(&dev);
    hipDeviceProp_t prop{};
    hipGetDeviceProperties(&prop, dev);
    int occ = 0;
    hipError_t e = hipOccupancyMaxActiveBlocksPerMultiprocessor(&occ, k_all, 256, 0);
    s_ok = (e == hipSuccess &&
            (long long)occ * prop.multiProcessorCount >= (long long)kB * kChunks)
               ? 1 : 0;
  }

  if (s_ok && ws_size >= WS_NEED_PARTIAL) {
    // zero the per-b barrier counters (workspace is poisoned every iteration)
    hipMemsetAsync((void*)(ws + OFF_BAR), 0, kB * 16 * sizeof(int), stream);
    k_all<<<dim3(kB, kChunks), 256, 0, stream>>>(
        x, W, b_caps, gamma, Wq, bq, Wk, bk, Wv_in, bv_in, Wo, bo, ln_g, ln_b,
        out, ws);
    return;
  }

  // fallback: round-1 verified multi-kernel path
  float* xpart = ws + OFF_XPART;
  float* v     = ws + OFF_V;
  float* Wv    = ws + OFF_WV;
  float* bv    = ws + OFF_BV;
  float* y     = ws + OFF_Y;
  float* cs    = ws + OFF_CS;
  float* ctx   = ws + OFF_CTX;
  f16*   xf16  = (f16*)(ws + OFF_XF16);
  f16*   wvh   = (f16*)(ws + OFF_WVH);
  float* csp   = ws + OFF_CSP;
  f16*   yp    = (f16*)(ws + OFF_YP);

  const int usePart = (ws_size >= WS_NEED_PARTIAL) ? 1 : 0;

  k_xpart<<<dim3(kB, kXJ), 256, 0, stream>>>(x, xpart, xf16);
  k_sv<<<kB * kC, 256, 0, stream>>>(W, b_caps, xpart, y, cs, yp, csp, v, Wv, wvh, bv,
                                    0, 1, 0, 0);
  if (!usePart) {
    hipMemsetAsync(y, 0, (size_t)kB * kC * kD * sizeof(float), stream);
    hipMemsetAsync(cs, 0, (size_t)kB * kC * sizeof(float), stream);
  }
  k_route<<<dim3(kB, kChunks), 256, 0, stream>>>(xf16, wvh, bv, y, cs, yp, csp, usePart);
  k_sv<<<kB * kC, 256, 0, stream>>>(W, b_caps, xpart, y, cs, yp, csp, v, Wv, wvh, bv,
                                    1, 1, 1, usePart ? kChunks : 0);
  if (!usePart) {
    hipMemsetAsync(y, 0, (size_t)kB * kC * kD * sizeof(float), stream);
    hipMemsetAsync(cs, 0, (size_t)kB * kC * sizeof(float), stream);
  }
  k_route<<<dim3(kB, kChunks), 256, 0, stream>>>(xf16, wvh, bv, y, cs, yp, csp, usePart);
  k_sv<<<kB * kC, 256, 0, stream>>>(W, b_caps, xpart, y, cs, yp, csp, v, Wv, wvh, bv,
                                    1, 0, 0, usePart ? kChunks : 0);
  k_attn<<<dim3(kB, kHeads), 256, 0, stream>>>(v, Wq, bq, Wk, bk, Wv_in, bv_in, ctx);
  k_final<<<kB * kC, 256, 0, stream>>>(ctx, Wo, bo, v, ln_g, ln_b, gamma, out);
}

// Round 4
// 173.445 us; speedup vs baseline: 1.0108x; 1.0108x over previous
//
#include <hip/hip_runtime.h>
#include <cstddef>

typedef _Float16 f16;
typedef __attribute__((ext_vector_type(8))) _Float16 f16x8;
typedef __attribute__((ext_vector_type(4))) float f32x4;

namespace {
constexpr int kB = 16;
constexpr int kN = 2048;
constexpr int kD = 256;   // D_IN
constexpr int kC = 32;
constexpr int kH = 64;
constexpr int kHeads = 4;
constexpr int kKD = 64;
constexpr int kChunks = 32;                  // n-chunks per b
constexpr int kRows = kN / kChunks;          // 64 rows per chunk
constexpr int kXJ = 64;                      // xpart sub-chunks (fallback path)

// workspace offsets (floats)
constexpr size_t OFF_XPART = 0;                       // fused: [B,32,D]; fallback: [B,64,D]
constexpr size_t OFF_V     = OFF_XPART + 262144;      // [B,C,H]
constexpr size_t OFF_WV    = OFF_V + 32768;           // [B,C,D] fp32
constexpr size_t OFF_BV    = OFF_WV + 131072;         // [B,C]
constexpr size_t OFF_Y     = OFF_BV + 512;            // [B,C,D] (fallback atomic)
constexpr size_t OFF_CS    = OFF_Y + 131072;          // [B,C]
constexpr size_t OFF_BAR   = OFF_CS + 512;            // barrier counters (16 × 16 ints)
constexpr size_t OFF_CTX   = OFF_BAR + 393216;        // [B,C,HEADS,KD]
constexpr size_t OFF_XF16  = OFF_CTX + 524288;        // [B,N,D] f16 (fallback only)
constexpr size_t OFF_WVH   = OFF_XF16 + 4194304;      // [B,C,D] f16
constexpr size_t OFF_CSP   = OFF_WVH + 65536;         // [B,chunks,C]
constexpr size_t OFF_YP    = OFF_CSP + 16384;         // [B,chunks,C,D] f16
constexpr size_t WS_NEED_PARTIAL = (OFF_YP + 4194304) * sizeof(float);

struct SMemR {                       // routing phases (A-F)
  f16 xsT[kD][kRows + 8];            // [256][72] transposed x (persistent A->E)
  float aL[kRows][kC + 4];           // [64][36] logits
  f16 pT[kC][kRows + 8];             // [32][72] P^T
  float csL[8][kC];
  float yL[kD];
  float sL[4][kH];
  float vL[kH];
  float csLs;
};
struct SMemA {                       // attention phase
  float rL[kC * kH];
  float qL[kC][kKD];
  float kL[kC][kKD + 1];
  float vL[kC][kKD];
  float sc[kC][kC + 1];
};
struct SMemF {                       // final phase
  float cL[kHeads * kKD];
  float sL[4][kH];
};
union SMemU { SMemR r; SMemA a; SMemF f; };
}  // namespace

// ---- per-b barrier, relaxed-spin protocol.
// Arrival: RELEASE fetch_add (publishes this block's stores: one L2 writeback).
// Poll: RELAXED agent-scope atomic loads — these bypass the non-coherent
// L1/L2 WITHOUT invalidating them (round-3's per-poll ACQUIRE emitted a
// buffer_inv each iteration: 512 leaders thrashing all 8 XCD L2s -> 23 us/bar).
// Every 256th poll uses ACQUIRE as a liveness hedge. One acquire fence after
// exit establishes the happens-before edge (release store -> relaxed load
// observes -> acquire fence) before __syncthreads releases the block.
__device__ __forceinline__ void bbar(int* __restrict__ bar, int b, int target) {
  __syncthreads();
  if (threadIdx.x == 0) {
    __hip_atomic_fetch_add(&bar[b * 16], 1, __ATOMIC_RELEASE,
                           __HIP_MEMORY_SCOPE_AGENT);
    int guard = 0;
    for (;;) {
      const int vv =
          ((guard & 255) == 255)
              ? __hip_atomic_load(&bar[b * 16], __ATOMIC_ACQUIRE,
                                  __HIP_MEMORY_SCOPE_AGENT)
              : __hip_atomic_load(&bar[b * 16], __ATOMIC_RELAXED,
                                  __HIP_MEMORY_SCOPE_AGENT);
      if (vv >= target) break;
      __builtin_amdgcn_s_sleep(1);
      if (++guard > (1 << 22)) break;
    }
    __builtin_amdgcn_fence(__ATOMIC_ACQUIRE, "agent");
  }
  __syncthreads();
}

// squash tail shared by sv phases. Requires sm.yL/csLs valid + __syncthreads done.
template <int CW, int ACC, int WRV>
__device__ __forceinline__ void sv_tail(const float* __restrict__ W,
                                        const float* __restrict__ b_caps,
                                        SMemR& r, float* __restrict__ v,
                                        float* __restrict__ Wv, f16* __restrict__ wvh,
                                        float* __restrict__ bv, int b, int c, int t) {
  const int w = t >> 6, h = t & 63;
  const float* Wc = W + (size_t)c * kD * kH;
  {
    float acc = 0.f;
#pragma unroll 8
    for (int d = w * 64; d < (w + 1) * 64; ++d)
      acc = fmaf(r.yL[d], Wc[(size_t)d * kH + h], acc);
    r.sL[w][h] = acc;
  }
  __syncthreads();
  if (t < 64) {
    const float bch = b_caps[c * kH + h];
    float s = r.sL[0][h] + r.sL[1][h] + r.sL[2][h] + r.sL[3][h] + r.csLs * bch;
    float s2 = s * s;
#pragma unroll
    for (int off = 32; off; off >>= 1) s2 += __shfl_xor(s2, off, 64);
    const float scale = s2 / (1.f + s2) * rsqrtf(s2 + 1e-7f);
    const float vh = scale * s;
    if (WRV) v[((size_t)b * kC + c) * kH + h] = vh;
    r.vL[h] = vh;
    if (CW) {
      float bvp = bch * vh;
#pragma unroll
      for (int off = 32; off; off >>= 1) bvp += __shfl_xor(bvp, off, 64);
      if (h == 0) bv[b * kC + c] = ACC ? (bv[b * kC + c] + bvp) : bvp;
    }
  }
  __syncthreads();
  if (CW) {
    float acc = 0.f;
    const float* Wrow = Wc + (size_t)t * kH;
#pragma unroll 8
    for (int hh = 0; hh < kH; ++hh) acc = fmaf(Wrow[hh], r.vL[hh], acc);
    const size_t idx = ((size_t)b * kC + c) * kD + t;
    const float nv = ACC ? (Wv[idx] + acc) : acc;
    Wv[idx] = nv;
    wvh[idx] = (f16)nv;
  }
}

// one routing iteration: GEMM1(af regs, wvh) -> softmax -> GEMM2(pT, xsT) -> partials
__device__ __forceinline__ void route_phase(SMemR& r, const f16x8* __restrict__ af,
                                            const f16* __restrict__ wvh,
                                            const float* __restrict__ bv,
                                            f16* __restrict__ yp, float* __restrict__ csp,
                                            int b, int chunk, int t) {
  const int lane = t & 63, w = t >> 6;
  const int l15 = lane & 15, q = lane >> 4;
  const float bvc = bv[b * kC + (t & 31)];

  f32x4 acc0 = {0.f, 0.f, 0.f, 0.f}, acc1 = {0.f, 0.f, 0.f, 0.f};
  {
    const f16x8* B0 = reinterpret_cast<const f16x8*>(
        wvh + ((size_t)(b * kC + l15)) * kD + q * 8);
    const f16x8* B1 = reinterpret_cast<const f16x8*>(
        wvh + ((size_t)(b * kC + 16 + l15)) * kD + q * 8);
#pragma unroll
    for (int ks = 0; ks < 8; ++ks) {
      acc0 = __builtin_amdgcn_mfma_f32_16x16x32_f16(af[ks], B0[ks * 4], acc0, 0, 0, 0);
      acc1 = __builtin_amdgcn_mfma_f32_16x16x32_f16(af[ks], B1[ks * 4], acc1, 0, 0, 0);
    }
  }
#pragma unroll
  for (int rr = 0; rr < 4; ++rr) {
    r.aL[w * 16 + q * 4 + rr][l15] = acc0[rr];
    r.aL[w * 16 + q * 4 + rr][16 + l15] = acc1[rr];
  }
  __syncthreads();  // aL visible

  const int c = t & 31, sg = t >> 5;
  float csreg = 0.f;
#pragma unroll
  for (int k = 0; k < 8; ++k) {
    const int rr = sg * 8 + k;
    float L = bvc + r.aL[rr][c];
    float m = L;
#pragma unroll
    for (int off = 16; off; off >>= 1) m = fmaxf(m, __shfl_xor(m, off, 64));
    const float e = __expf(L - m);
    float ssum = e;
#pragma unroll
    for (int off = 16; off; off >>= 1) ssum += __shfl_xor(ssum, off, 64);
    const float p = e / ssum;
    r.pT[c][rr] = (f16)p;
    csreg += p;
  }
  r.csL[sg][c] = csreg;
  __syncthreads();  // pT visible

  const int mt2 = w & 1;
  const int ntb = (w >> 1) * 8;
  const f16x8 a0 = *reinterpret_cast<const f16x8*>(&r.pT[mt2 * 16 + l15][q * 8]);
  const f16x8 a1 = *reinterpret_cast<const f16x8*>(&r.pT[mt2 * 16 + l15][32 + q * 8]);
  const int cap = mt2 * 16 + q * 4;
#pragma unroll
  for (int i = 0; i < 8; ++i) {
    const int d0 = (ntb + i) * 16;
    const f16x8 b0 = *reinterpret_cast<const f16x8*>(&r.xsT[d0 + l15][q * 8]);
    const f16x8 b1 = *reinterpret_cast<const f16x8*>(&r.xsT[d0 + l15][32 + q * 8]);
    f32x4 o = {0.f, 0.f, 0.f, 0.f};
    o = __builtin_amdgcn_mfma_f32_16x16x32_f16(a0, b0, o, 0, 0, 0);
    o = __builtin_amdgcn_mfma_f32_16x16x32_f16(a1, b1, o, 0, 0, 0);
    f16* dst = yp + (((size_t)(b * kChunks + chunk)) * kC + cap) * kD + d0 + l15;
#pragma unroll
    for (int rr = 0; rr < 4; ++rr) dst[(size_t)rr * kD] = (f16)o[rr];
  }
  if (t < 32) {
    float s = 0.f;
#pragma unroll
    for (int j = 0; j < 8; ++j) s += r.csL[j][t];
    csp[((size_t)b * kChunks + chunk) * kC + t] = s;
  }
}

__global__ __launch_bounds__(256, 2) void k_all(
    const float* __restrict__ x, const float* __restrict__ W,
    const float* __restrict__ b_caps, const float* __restrict__ gamma,
    const float* __restrict__ Wq, const float* __restrict__ bq,
    const float* __restrict__ Wk, const float* __restrict__ bk,
    const float* __restrict__ Wvp, const float* __restrict__ bvp,
    const float* __restrict__ Wo, const float* __restrict__ bo,
    const float* __restrict__ ln_g, const float* __restrict__ ln_b,
    float* __restrict__ out, float* __restrict__ ws) {
  float* xpart = ws + OFF_XPART;   // [B,32,D] per-chunk column sums
  float* v     = ws + OFF_V;
  float* Wv    = ws + OFF_WV;
  float* bv    = ws + OFF_BV;
  int*   bar   = (int*)(ws + OFF_BAR);
  float* ctx   = ws + OFF_CTX;
  f16*   wvh   = (f16*)(ws + OFF_WVH);
  float* csp   = ws + OFF_CSP;
  f16*   yp    = (f16*)(ws + OFF_YP);

  const int b = blockIdx.x, chunk = blockIdx.y;
  const int t = threadIdx.x;
  const int lane = t & 63, w = t >> 6;
  const int l15 = lane & 15, q = lane >> 4;
  const int n0 = chunk * kRows;
  const int c = chunk;  // capsule index for sv phases

  __shared__ __align__(16) SMemU sm;

  // ---- Phase A: column partial sums (fp32) + stage x chunk: af regs + xsT LDS
  {
    const float* xc = x + ((size_t)b * kN + n0) * kD + t;
    float s = 0.f;
#pragma unroll 16
    for (int n = 0; n < kRows; ++n) s += xc[(size_t)n * kD];
    xpart[((size_t)b * kChunks + chunk) * kD + t] = s;
  }
  f16x8 af[8];
  {
    const int row = w * 16 + l15;
    const float* xr = x + ((size_t)(b * kN + n0 + row)) * kD + q * 8;
#pragma unroll
    for (int ks = 0; ks < 8; ++ks) {
      const f32x4* p = reinterpret_cast<const f32x4*>(xr + ks * 32);
      const f32x4 lo = p[0], hi = p[1];
      f16x8 a;
      a[0] = (f16)lo[0]; a[1] = (f16)lo[1]; a[2] = (f16)lo[2]; a[3] = (f16)lo[3];
      a[4] = (f16)hi[0]; a[5] = (f16)hi[1]; a[6] = (f16)hi[2]; a[7] = (f16)hi[3];
      af[ks] = a;
      const int dbase = ks * 32 + q * 8;
#pragma unroll
      for (int i = 0; i < 8; ++i) {
        const int ii = (i + 2 * q) & 7;  // rotate: distinct banks across q-groups
        sm.r.xsT[dbase + ii][row] = a[ii];
      }
    }
  }
  bbar(bar, b, 32 * 1);

  // ---- Phase B: sv mode0 (y = colsum/C), compute v, Wv, wvh, bv
  {
    float s = 0.f;
#pragma unroll 8
    for (int ch = 0; ch < kChunks; ++ch)
      s += xpart[((size_t)b * kChunks + ch) * kD + t];
    sm.r.yL[t] = s * (1.f / (float)kC);
    if (t == 0) sm.r.csLs = (float)kN / (float)kC;
  }
  __syncthreads();
  sv_tail<1, 0, 0>(W, b_caps, sm.r, v, Wv, wvh, bv, b, c, t);
  bbar(bar, b, 32 * 2);

  // ---- Phase C: routing iteration 1
  route_phase(sm.r, af, wvh, bv, yp, csp, b, chunk, t);
  bbar(bar, b, 32 * 3);

  // ---- Phase D: sv from partials, accumulate Wv/bv
  {
    float s = 0.f;
#pragma unroll 8
    for (int ch = 0; ch < kChunks; ++ch)
      s += (float)yp[(((size_t)b * kChunks + ch) * kC + c) * kD + t];
    sm.r.yL[t] = s;
    if (t < 32) {
      float cs_ = csp[((size_t)b * kChunks + t) * kC + c];
#pragma unroll
      for (int off = 16; off; off >>= 1) cs_ += __shfl_xor(cs_, off, 64);
      if (t == 0) sm.r.csLs = cs_;
    }
  }
  __syncthreads();
  sv_tail<1, 1, 0>(W, b_caps, sm.r, v, Wv, wvh, bv, b, c, t);
  bbar(bar, b, 32 * 4);

  // ---- Phase E: routing iteration 2
  route_phase(sm.r, af, wvh, bv, yp, csp, b, chunk, t);
  bbar(bar, b, 32 * 5);

  // ---- Phase F: final sv -> v (routed) to global
  {
    float s = 0.f;
#pragma unroll 8
    for (int ch = 0; ch < kChunks; ++ch)
      s += (float)yp[(((size_t)b * kChunks + ch) * kC + c) * kD + t];
    sm.r.yL[t] = s;
    if (t < 32) {
      float cs_ = csp[((size_t)b * kChunks + t) * kC + c];
#pragma unroll
      for (int off = 16; off; off >>= 1) cs_ += __shfl_xor(cs_, off, 64);
      if (t == 0) sm.r.csLs = cs_;
    }
  }
  __syncthreads();
  sv_tail<0, 0, 1>(W, b_caps, sm.r, v, Wv, wvh, bv, b, c, t);
  bbar(bar, b, 32 * 6);

  // ---- Phase G: attention (blocks with chunk < kHeads participate; head = chunk)
  if (chunk < kHeads) {
    const int head = chunk;
    const int kk = t & 63;
#pragma unroll
    for (int i = 0; i < 8; ++i)
      sm.a.rL[t + 256 * i] = v[(size_t)b * kC * kH + t + 256 * i];
    __syncthreads();
    float aq[8], ak[8], av[8];
    const float bbq = bq[head * kKD + kk];
    const float bbk = bk[head * kKD + kk];
    const float bbv = bvp[head * kKD + kk];
#pragma unroll
    for (int i = 0; i < 8; ++i) { aq[i] = bbq; ak[i] = bbk; av[i] = bbv; }
#pragma unroll 4
    for (int hh = 0; hh < kH; ++hh) {
      const size_t widx = ((size_t)hh * kHeads + head) * kKD + kk;
      const float wq = Wq[widx];
      const float wk2 = Wk[widx];
      const float wv2 = Wvp[widx];
#pragma unroll
      for (int i = 0; i < 8; ++i) {
        const float rv = sm.a.rL[(w + 4 * i) * kH + hh];
        aq[i] = fmaf(rv, wq, aq[i]);
        ak[i] = fmaf(rv, wk2, ak[i]);
        av[i] = fmaf(rv, wv2, av[i]);
      }
    }
#pragma unroll
    for (int i = 0; i < 8; ++i) {
      const int cc = w + 4 * i;
      sm.a.qL[cc][kk] = aq[i];
      sm.a.kL[cc][kk] = ak[i];
      sm.a.vL[cc][kk] = av[i];
    }
    __syncthreads();
#pragma unroll
    for (int i = 0; i < 4; ++i) {
      const int e = t + 256 * i, qc = e >> 5, kc2 = e & 31;
      float s = 0.f;
#pragma unroll 8
      for (int d = 0; d < kKD; ++d) s = fmaf(sm.a.qL[qc][d], sm.a.kL[kc2][d], s);
      sm.a.sc[qc][kc2] = s * 0.125f;
    }
    __syncthreads();
    if (t < kC) {
      float m = -1e30f;
#pragma unroll
      for (int kc2 = 0; kc2 < kC; ++kc2) m = fmaxf(m, sm.a.sc[t][kc2]);
      float ssum = 0.f;
#pragma unroll
      for (int kc2 = 0; kc2 < kC; ++kc2) {
        const float e2 = __expf(sm.a.sc[t][kc2] - m);
        sm.a.sc[t][kc2] = e2;
        ssum += e2;
      }
      const float inv = 1.f / ssum;
#pragma unroll
      for (int kc2 = 0; kc2 < kC; ++kc2) sm.a.sc[t][kc2] *= inv;
    }
    __syncthreads();
#pragma unroll
    for (int i = 0; i < 8; ++i) {
      const int e = t + 256 * i, qc = e >> 6, d = e & 63;
      float s = 0.f;
#pragma unroll 8
      for (int kc2 = 0; kc2 < kC; ++kc2) s = fmaf(sm.a.sc[qc][kc2], sm.a.vL[kc2][d], s);
      ctx[(((size_t)b * kC + qc) * kHeads + head) * kKD + d] = s;
    }
  }
  bbar(bar, b, 32 * 7);

  // ---- Phase H: out-proj + residual + LN + squash*gamma (block = (b, c))
  {
    const int bc = b * kC + chunk;
    const int h = t & 63;
    sm.f.cL[t] = ctx[(size_t)bc * (kHeads * kKD) + t];
    __syncthreads();
    float acc = 0.f;
#pragma unroll 8
    for (int nd = w * 64; nd < (w + 1) * 64; ++nd)
      acc = fmaf(sm.f.cL[nd], Wo[(size_t)nd * kH + h], acc);
    sm.f.sL[w][h] = acc;
    __syncthreads();
    if (t < 64) {
      const float yv = sm.f.sL[0][h] + sm.f.sL[1][h] + sm.f.sL[2][h] + sm.f.sL[3][h] +
                       bo[h] + v[(size_t)bc * kH + h];
      float mu = yv;
#pragma unroll
      for (int off = 32; off; off >>= 1) mu += __shfl_xor(mu, off, 64);
      mu *= (1.f / (float)kH);
      const float dv = yv - mu;
      float var = dv * dv;
#pragma unroll
      for (int off = 32; off; off >>= 1) var += __shfl_xor(var, off, 64);
      var *= (1.f / (float)kH);
      const float nrm = dv * rsqrtf(var + 1e-3f) * ln_g[h] + ln_b[h];
      float s2 = nrm * nrm;
#pragma unroll
      for (int off = 32; off; off >>= 1) s2 += __shfl_xor(s2, off, 64);
      const float scale = s2 / (1.f + s2) * rsqrtf(s2 + 1e-7f);
      out[(size_t)bc * kH + h] = scale * nrm * gamma[0];
    }
  }
}

// ======================= fallback multi-kernel path (round-1, verified) =======================

__global__ __launch_bounds__(256) void k_xpart(const float* __restrict__ x,
                                               float* __restrict__ xpart,
                                               f16* __restrict__ xh) {
  const int b = blockIdx.x, j = blockIdx.y, d = threadIdx.x;
  const size_t base = ((size_t)b * kN + (size_t)j * 32) * kD + d;
  const float* xp = x + base;
  f16* xo = xh + base;
  float s = 0.f;
#pragma unroll
  for (int n = 0; n < 32; ++n) {
    const float v = xp[(size_t)n * kD];
    s += v;
    xo[(size_t)n * kD] = (f16)v;
  }
  xpart[((size_t)b * kXJ + j) * kD + d] = s;
}

__global__ __launch_bounds__(256) void k_sv(
    const float* __restrict__ W, const float* __restrict__ b_caps,
    const float* __restrict__ xpart, const float* __restrict__ y,
    const float* __restrict__ csum, const f16* __restrict__ ypart,
    const float* __restrict__ cspart, float* __restrict__ v,
    float* __restrict__ Wv, f16* __restrict__ Wvh, float* __restrict__ bv,
    const int mode, const int computeWv, const int accWv, const int npart) {
  const int bc = blockIdx.x, b = bc >> 5, c = bc & 31;
  const int t = threadIdx.x;
  const int w = t >> 6, h = t & 63;
  __shared__ float yL[kD];
  __shared__ float sL[4][kH];
  __shared__ float vL[kH];
  __shared__ float csLs;

  if (mode == 0) {
    float s = 0.f;
#pragma unroll 8
    for (int j = 0; j < kXJ; ++j) s += xpart[((size_t)b * kXJ + j) * kD + t];
    yL[t] = s * (1.f / (float)kC);
    if (t == 0) csLs = (float)kN / (float)kC;
  } else if (npart > 0) {
    float s = 0.f;
#pragma unroll 8
    for (int ch = 0; ch < kChunks; ++ch)
      s += (float)ypart[(((size_t)b * kChunks + ch) * kC + c) * kD + t];
    yL[t] = s;
    if (t < 32) {
      float cs_ = cspart[((size_t)b * kChunks + t) * kC + c];
#pragma unroll
      for (int off = 16; off; off >>= 1) cs_ += __shfl_xor(cs_, off, 64);
      if (t == 0) csLs = cs_;
    }
  } else {
    yL[t] = y[(size_t)bc * kD + t];
    if (t == 0) csLs = csum[bc];
  }
  __syncthreads();

  const float* Wc = W + (size_t)c * kD * kH;
  {
    float acc = 0.f;
#pragma unroll 8
    for (int d = w * 64; d < (w + 1) * 64; ++d)
      acc = fmaf(yL[d], Wc[(size_t)d * kH + h], acc);
    sL[w][h] = acc;
  }
  __syncthreads();

  if (t < 64) {
    const float bch = b_caps[c * kH + h];
    float s = sL[0][h] + sL[1][h] + sL[2][h] + sL[3][h] + csLs * bch;
    float s2 = s * s;
#pragma unroll
    for (int off = 32; off; off >>= 1) s2 += __shfl_xor(s2, off, 64);
    const float scale = s2 / (1.f + s2) * rsqrtf(s2 + 1e-7f);
    const float vh = scale * s;
    v[(size_t)bc * kH + h] = vh;
    vL[h] = vh;
    if (computeWv) {
      float bvp = bch * vh;
#pragma unroll
      for (int off = 32; off; off >>= 1) bvp += __shfl_xor(bvp, off, 64);
      if (h == 0) bv[bc] = accWv ? (bv[bc] + bvp) : bvp;
    }
  }
  __syncthreads();
  if (computeWv) {
    float acc = 0.f;
    const float* Wrow = Wc + (size_t)t * kH;
#pragma unroll 8
    for (int hh = 0; hh < kH; ++hh) acc = fmaf(Wrow[hh], vL[hh], acc);
    const size_t idx = (size_t)bc * kD + t;
    const float nv = accWv ? (Wv[idx] + acc) : acc;
    Wv[idx] = nv;
    Wvh[idx] = (f16)nv;
  }
}

__global__ __launch_bounds__(256) void k_route(
    const f16* __restrict__ xh, const f16* __restrict__ Wvh,
    const float* __restrict__ bv, float* __restrict__ y,
    float* __restrict__ csum, f16* __restrict__ ypart,
    float* __restrict__ cspart, const int usePart) {
  const int b = blockIdx.x, chunk = blockIdx.y;
  const int t = threadIdx.x;
  const int lane = t & 63, w = t >> 6;
  const int l15 = lane & 15, q = lane >> 4;

  __shared__ __align__(16) f16 xsT[kD][kRows + 8];
  __shared__ float aL[kRows][kC + 4];
  __shared__ __align__(16) f16 pT[kC][kRows + 8];
  __shared__ float csL[8][kC];

  const int n0 = chunk * kRows;
  const float bvc = bv[b * kC + (t & 31)];

  f32x4 acc0 = {0.f, 0.f, 0.f, 0.f}, acc1 = {0.f, 0.f, 0.f, 0.f};
  {
    const int row = w * 16 + l15;
    const f16x8* Ar = reinterpret_cast<const f16x8*>(
        xh + ((size_t)(b * kN + n0 + row)) * kD + q * 8);
    const f16x8* B0 = reinterpret_cast<const f16x8*>(
        Wvh + ((size_t)(b * kC + l15)) * kD + q * 8);
    const f16x8* B1 = reinterpret_cast<const f16x8*>(
        Wvh + ((size_t)(b * kC + 16 + l15)) * kD + q * 8);
#pragma unroll
    for (int ks = 0; ks < 8; ++ks) {
      f16x8 af = Ar[ks * 4];
      acc0 = __builtin_amdgcn_mfma_f32_16x16x32_f16(af, B0[ks * 4], acc0, 0, 0, 0);
      acc1 = __builtin_amdgcn_mfma_f32_16x16x32_f16(af, B1[ks * 4], acc1, 0, 0, 0);
      const int dbase = ks * 32 + q * 8;
#pragma unroll
      for (int i = 0; i < 8; ++i) {
        const int ii = (i + 2 * q) & 7;
        xsT[dbase + ii][row] = af[ii];
      }
    }
  }
#pragma unroll
  for (int r = 0; r < 4; ++r) {
    aL[w * 16 + q * 4 + r][l15] = acc0[r];
    aL[w * 16 + q * 4 + r][16 + l15] = acc1[r];
  }
  __syncthreads();

  const int c = t & 31, sg = t >> 5;
  float csreg = 0.f;
#pragma unroll
  for (int k = 0; k < 8; ++k) {
    const int r = sg * 8 + k;
    float L = bvc + aL[r][c];
    float m = L;
#pragma unroll
    for (int off = 16; off; off >>= 1) m = fmaxf(m, __shfl_xor(m, off, 64));
    const float e = __expf(L - m);
    float ssum = e;
#pragma unroll
    for (int off = 16; off; off >>= 1) ssum += __shfl_xor(ssum, off, 64);
    const float p = e / ssum;
    pT[c][r] = (f16)p;
    csreg += p;
  }
  csL[sg][c] = csreg;
  __syncthreads();

  const int mt2 = w & 1;
  const int ntb = (w >> 1) * 8;
  const f16x8 a0 = *reinterpret_cast<const f16x8*>(&pT[mt2 * 16 + l15][q * 8]);
  const f16x8 a1 = *reinterpret_cast<const f16x8*>(&pT[mt2 * 16 + l15][32 + q * 8]);
  const int cap = mt2 * 16 + q * 4;
#pragma unroll
  for (int i = 0; i < 8; ++i) {
    const int d0 = (ntb + i) * 16;
    const f16x8 b0 = *reinterpret_cast<const f16x8*>(&xsT[d0 + l15][q * 8]);
    const f16x8 b1 = *reinterpret_cast<const f16x8*>(&xsT[d0 + l15][32 + q * 8]);
    f32x4 o = {0.f, 0.f, 0.f, 0.f};
    o = __builtin_amdgcn_mfma_f32_16x16x32_f16(a0, b0, o, 0, 0, 0);
    o = __builtin_amdgcn_mfma_f32_16x16x32_f16(a1, b1, o, 0, 0, 0);
    if (usePart) {
      f16* dst = ypart + (((size_t)(b * kChunks + chunk)) * kC + cap) * kD + d0 + l15;
#pragma unroll
      for (int r = 0; r < 4; ++r) dst[(size_t)r * kD] = (f16)o[r];
    } else {
      float* dst = y + ((size_t)(b * kC + cap)) * kD + d0 + l15;
#pragma unroll
      for (int r = 0; r < 4; ++r) atomicAdd(dst + (size_t)r * kD, o[r]);
    }
  }
  if (t < 32) {
    float s = 0.f;
#pragma unroll
    for (int j = 0; j < 8; ++j) s += csL[j][t];
    if (usePart) cspart[((size_t)b * kChunks + chunk) * kC + t] = s;
    else atomicAdd(csum + b * kC + t, s);
  }
}

__global__ __launch_bounds__(256) void k_attn(
    const float* __restrict__ routed,
    const float* __restrict__ Wq, const float* __restrict__ bq,
    const float* __restrict__ Wk, const float* __restrict__ bk,
    const float* __restrict__ Wvp, const float* __restrict__ bvp,
    float* __restrict__ ctx) {
  const int b = blockIdx.x, head = blockIdx.y, t = threadIdx.x;
  const int kk = t & 63, w = t >> 6;
  __shared__ float rL[kC * kH];
  __shared__ float qL[kC][kKD];
  __shared__ float kL[kC][kKD + 1];
  __shared__ float vL[kC][kKD];
  __shared__ float sc[kC][kC + 1];
#pragma unroll
  for (int i = 0; i < 8; ++i) rL[t + 256 * i] = routed[(size_t)b * kC * kH + t + 256 * i];
  __syncthreads();
  float aq[8], ak[8], av[8];
  const float bbq = bq[head * kKD + kk];
  const float bbk = bk[head * kKD + kk];
  const float bbv = bvp[head * kKD + kk];
#pragma unroll
  for (int i = 0; i < 8; ++i) { aq[i] = bbq; ak[i] = bbk; av[i] = bbv; }
#pragma unroll 4
  for (int hh = 0; hh < kH; ++hh) {
    const size_t widx = ((size_t)hh * kHeads + head) * kKD + kk;
    const float wq = Wq[widx];
    const float wk2 = Wk[widx];
    const float wv2 = Wvp[widx];
#pragma unroll
    for (int i = 0; i < 8; ++i) {
      const float r = rL[(w + 4 * i) * kH + hh];
      aq[i] = fmaf(r, wq, aq[i]);
      ak[i] = fmaf(r, wk2, ak[i]);
      av[i] = fmaf(r, wv2, av[i]);
    }
  }
#pragma unroll
  for (int i = 0; i < 8; ++i) {
    const int cc = w + 4 * i;
    qL[cc][kk] = aq[i];
    kL[cc][kk] = ak[i];
    vL[cc][kk] = av[i];
  }
  __syncthreads();
#pragma unroll
  for (int i = 0; i < 4; ++i) {
    const int e = t + 256 * i, qc = e >> 5, kc2 = e & 31;
    float s = 0.f;
#pragma unroll 8
    for (int d = 0; d < kKD; ++d) s = fmaf(qL[qc][d], kL[kc2][d], s);
    sc[qc][kc2] = s * 0.125f;
  }
  __syncthreads();
  if (t < kC) {
    float m = -1e30f;
#pragma unroll
    for (int kc2 = 0; kc2 < kC; ++kc2) m = fmaxf(m, sc[t][kc2]);
    float ssum = 0.f;
#pragma unroll
    for (int kc2 = 0; kc2 < kC; ++kc2) {
      const float e2 = __expf(sc[t][kc2] - m);
      sc[t][kc2] = e2;
      ssum += e2;
    }
    const float inv = 1.f / ssum;
#pragma unroll
    for (int kc2 = 0; kc2 < kC; ++kc2) sc[t][kc2] *= inv;
  }
  __syncthreads();
#pragma unroll
  for (int i = 0; i < 8; ++i) {
    const int e = t + 256 * i, qc = e >> 6, d = e & 63;
    float s = 0.f;
#pragma unroll 8
    for (int kc2 = 0; kc2 < kC; ++kc2) s = fmaf(sc[qc][kc2], vL[kc2][d], s);
    ctx[(((size_t)b * kC + qc) * kHeads + head) * kKD + d] = s;
  }
}

__global__ __launch_bounds__(256) void k_final(
    const float* __restrict__ ctx, const float* __restrict__ Wo,
    const float* __restrict__ bo, const float* __restrict__ routed,
    const float* __restrict__ ln_g, const float* __restrict__ ln_b,
    const float* __restrict__ gamma, float* __restrict__ out) {
  const int bc = blockIdx.x, t = threadIdx.x;
  const int w = t >> 6, h = t & 63;
  __shared__ float cL[kHeads * kKD];
  __shared__ float sL[4][kH];
  cL[t] = ctx[(size_t)bc * (kHeads * kKD) + t];
  __syncthreads();
  float acc = 0.f;
#pragma unroll 8
  for (int nd = w * 64; nd < (w + 1) * 64; ++nd)
    acc = fmaf(cL[nd], Wo[(size_t)nd * kH + h], acc);
  sL[w][h] = acc;
  __syncthreads();
  if (t < 64) {
    const float yv = sL[0][h] + sL[1][h] + sL[2][h] + sL[3][h] + bo[h] +
                     routed[(size_t)bc * kH + h];
    float mu = yv;
#pragma unroll
    for (int off = 32; off; off >>= 1) mu += __shfl_xor(mu, off, 64);
    mu *= (1.f / (float)kH);
    const float dv = yv - mu;
    float var = dv * dv;
#pragma unroll
    for (int off = 32; off; off >>= 1) var += __shfl_xor(var, off, 64);
    var *= (1.f / (float)kH);
    const float nrm = dv * rsqrtf(var + 1e-3f) * ln_g[h] + ln_b[h];
    float s2 = nrm * nrm;
#pragma unroll
    for (int off = 32; off; off >>= 1) s2 += __shfl_xor(s2, off, 64);
    const float scale = s2 / (1.f + s2) * rsqrtf(s2 + 1e-7f);
    out[(size_t)bc * kH + h] = scale * nrm * gamma[0];
  }
}

extern "C" void kernel_launch(void* const* d_in, const int* in_sizes, int n_in,
                              void* d_out, int out_size, void* d_ws, size_t ws_size,
                              hipStream_t stream) {
  (void)in_sizes; (void)n_in; (void)out_size;
  const float* x      = (const float*)d_in[0];
  const float* W      = (const float*)d_in[1];
  const float* b_caps = (const float*)d_in[2];
  const float* gamma  = (const float*)d_in[3];
  const float* Wq     = (const float*)d_in[4];
  const float* bq     = (const float*)d_in[5];
  const float* Wk     = (const float*)d_in[6];
  const float* bk     = (const float*)d_in[7];
  const float* Wv_in  = (const float*)d_in[8];
  const float* bv_in  = (const float*)d_in[9];
  const float* Wo     = (const float*)d_in[10];
  const float* bo     = (const float*)d_in[11];
  const float* ln_g   = (const float*)d_in[12];
  const float* ln_b   = (const float*)d_in[13];
  float* out = (float*)d_out;
  float* ws  = (float*)d_ws;

  // one-time co-residency check for the persistent fused kernel (regular launch)
  static int s_ok = -1;
  if (s_ok < 0) {
    int dev = 0;
    hipGetDevice(&dev);
    hipDeviceProp_t prop{};
    hipGetDeviceProperties(&prop, dev);
    int occ = 0;
    hipError_t e = hipOccupancyMaxActiveBlocksPerMultiprocessor(&occ, k_all, 256, 0);
    s_ok = (e == hipSuccess &&
            (long long)occ * prop.multiProcessorCount >= (long long)kB * kChunks)
               ? 1 : 0;
  }

  if (s_ok && ws_size >= WS_NEED_PARTIAL) {
    // zero the per-b barrier counters (workspace is poisoned every iteration)
    hipMemsetAsync((void*)(ws + OFF_BAR), 0, kB * 16 * sizeof(int), stream);
    k_all<<<dim3(kB, kChunks), 256, 0, stream>>>(
        x, W, b_caps, gamma, Wq, bq, Wk, bk, Wv_in, bv_in, Wo, bo, ln_g, ln_b,
        out, ws);
    return;
  }

  // fallback: round-1 verified multi-kernel path
  float* xpart = ws + OFF_XPART;
  float* v     = ws + OFF_V;
  float* Wv    = ws + OFF_WV;
  float* bv    = ws + OFF_BV;
  float* y     = ws + OFF_Y;
  float* cs    = ws + OFF_CS;
  float* ctx   = ws + OFF_CTX;
  f16*   xf16  = (f16*)(ws + OFF_XF16);
  f16*   wvh   = (f16*)(ws + OFF_WVH);
  float* csp   = ws + OFF_CSP;
  f16*   yp    = (f16*)(ws + OFF_YP);

  const int usePart = (ws_size >= WS_NEED_PARTIAL) ? 1 : 0;

  k_xpart<<<dim3(kB, kXJ), 256, 0, stream>>>(x, xpart, xf16);
  k_sv<<<kB * kC, 256, 0, stream>>>(W, b_caps, xpart, y, cs, yp, csp, v, Wv, wvh, bv,
                                    0, 1, 0, 0);
  if (!usePart) {
    hipMemsetAsync(y, 0, (size_t)kB * kC * kD * sizeof(float), stream);
    hipMemsetAsync(cs, 0, (size_t)kB * kC * sizeof(float), stream);
  }
  k_route<<<dim3(kB, kChunks), 256, 0, stream>>>(xf16, wvh, bv, y, cs, yp, csp, usePart);
  k_sv<<<kB * kC, 256, 0, stream>>>(W, b_caps, xpart, y, cs, yp, csp, v, Wv, wvh, bv,
                                    1, 1, 1, usePart ? kChunks : 0);
  if (!usePart) {
    hipMemsetAsync(y, 0, (size_t)kB * kC * kD * sizeof(float), stream);
    hipMemsetAsync(cs, 0, (size_t)kB * kC * sizeof(float), stream);
  }
  k_route<<<dim3(kB, kChunks), 256, 0, stream>>>(xf16, wvh, bv, y, cs, yp, csp, usePart);
  k_sv<<<kB * kC, 256, 0, stream>>>(W, b_caps, xpart, y, cs, yp, csp, v, Wv, wvh, bv,
                                    1, 0, 0, usePart ? kChunks : 0);
  k_attn<<<dim3(kB, kHeads), 256, 0, stream>>>(v, Wq, bq, Wk, bk, Wv_in, bv_in, ctx);
  k_final<<<kB * kC, 256, 0, stream>>>(ctx, Wo, bo, v, ln_g, ln_b, gamma, out);
}